// Round 1
// baseline (1144.893 us; speedup 1.0000x reference)
//
#include <hip/hip_runtime.h>
#include <stdint.h>

#define BATCH 256
#define SEQ   512
#define INDIM 64
#define HID   512

#define NREG   368                 // W_hh columns kept in registers (per row)
#define NLDS   (HID - NREG)        // 144 columns in LDS
#define NREG_C (NREG / 8)          // 46 chunks of 8
#define NLDS_C (NLDS / 8)          // 18 chunks of 8
#define NGROUPS (SEQ / 8)          // 64 x-prefetch groups

typedef _Float16 half2_t __attribute__((ext_vector_type(2)));

__device__ __forceinline__ float dot2f(uint32_t w, uint32_t h, float acc) {
    // v_dot2_f32_f16: 2 f16 MACs, f32 accumulate
    return __builtin_amdgcn_fdot2(__builtin_bit_cast(half2_t, w),
                                  __builtin_bit_cast(half2_t, h),
                                  acc, false);
}

__device__ __forceinline__ uint32_t pack2(float a, float b) {
    half2_t h;
    h[0] = (_Float16)a;
    h[1] = (_Float16)b;
    return __builtin_bit_cast(uint32_t, h);
}

struct SmemLayout {
    // W_hh cols [NREG,512) for all rows: chunk-major [NLDS_C][HID][8] halves.
    // Thread t only reads/writes its own row slots: 16B stride across lanes,
    // conflict-free ds_read_b128.
    _Float16 wlds[NLDS_C * HID * 8];   // 144 KB
    _Float16 hbuf[2][HID];             // double-buffered hidden state (f16), 2 KB
    _Float16 xbuf[2][8][INDIM];        // 2 groups x 8 steps x 64 inputs (f16), 2 KB
};

__global__ __launch_bounds__(512, 2)
void rnn_persist_kernel(const float* __restrict__ x,
                        const float* __restrict__ h0,
                        const float* __restrict__ W_ih,
                        const float* __restrict__ W_hh,
                        const float* __restrict__ b_ih,
                        const float* __restrict__ b_hh,
                        float* __restrict__ out)
{
    __shared__ SmemLayout sm;
    const int tid = threadIdx.x;      // owns hidden row `tid`
    const int b   = blockIdx.x;       // owns batch element `b`

    // ---------------- startup: load weights (one-time, L2/L3-fed) ----------
    const float* wrow = W_hh + (size_t)tid * HID;

    uint32_t wreg[NREG / 2];          // 184 VGPRs of packed f16x2
    #pragma unroll
    for (int c = 0; c < NREG_C; ++c) {
        float4 a  = ((const float4*)wrow)[2 * c];
        float4 bb = ((const float4*)wrow)[2 * c + 1];
        wreg[4 * c + 0] = pack2(a.x, a.y);
        wreg[4 * c + 1] = pack2(a.z, a.w);
        wreg[4 * c + 2] = pack2(bb.x, bb.y);
        wreg[4 * c + 3] = pack2(bb.z, bb.w);
    }

    const float* wtail = wrow + NREG;
    #pragma unroll
    for (int c = 0; c < NLDS_C; ++c) {
        float4 a  = ((const float4*)wtail)[2 * c];
        float4 bb = ((const float4*)wtail)[2 * c + 1];
        uint4 wv;
        wv.x = pack2(a.x, a.y);
        wv.y = pack2(a.z, a.w);
        wv.z = pack2(bb.x, bb.y);
        wv.w = pack2(bb.z, bb.w);
        *(uint4*)&sm.wlds[(size_t)(c * HID + tid) * 8] = wv;
    }

    const float* irow = W_ih + (size_t)tid * INDIM;
    uint32_t wih[INDIM / 2];          // 32 VGPRs
    #pragma unroll
    for (int c = 0; c < 8; ++c) {
        float4 a  = ((const float4*)irow)[2 * c];
        float4 bb = ((const float4*)irow)[2 * c + 1];
        wih[4 * c + 0] = pack2(a.x, a.y);
        wih[4 * c + 1] = pack2(a.z, a.w);
        wih[4 * c + 2] = pack2(bb.x, bb.y);
        wih[4 * c + 3] = pack2(bb.z, bb.w);
    }

    const float bsum = b_ih[tid] + b_hh[tid];

    float hval = h0[(size_t)b * HID + tid];
    sm.hbuf[0][tid] = (_Float16)hval;

    // stage x group 0 (8 steps): thread -> (row r, col c)
    {
        const int r = tid >> 6, c = tid & 63;
        float v = x[((size_t)b * SEQ + r) * INDIM + c];
        sm.xbuf[0][r][c] = (_Float16)v;
    }
    __syncthreads();

    // ---------------- 512 sequential steps ---------------------------------
    float xnext = 0.0f;
    #pragma unroll 1
    for (int t = 0; t < SEQ; ++t) {
        const int g    = t >> 3;
        const int lt   = t & 7;
        const int p    = t & 1;        // read hbuf[p], write hbuf[1-p]
        const int slot = g & 1;

        // issue next x-group loads early; latency hidden under ~5 steps
        if (lt == 0 && g + 1 < NGROUPS) {
            const int r = tid >> 6, c = tid & 63;
            xnext = x[((size_t)b * SEQ + (size_t)(g + 1) * 8 + r) * INDIM + c];
        }

        float acc = bsum;

        // x_proj: dot(W_ih[tid,:], x_t)  -- 32 dot2
        const uint4* xb4 = (const uint4*)&sm.xbuf[slot][lt][0];
        #pragma unroll
        for (int k = 0; k < 8; ++k) {
            uint4 xc = xb4[k];
            acc = dot2f(wih[4 * k + 0], xc.x, acc);
            acc = dot2f(wih[4 * k + 1], xc.y, acc);
            acc = dot2f(wih[4 * k + 2], xc.z, acc);
            acc = dot2f(wih[4 * k + 3], xc.w, acc);
        }

        const uint4* hb4 = (const uint4*)&sm.hbuf[p][0];

        // register-resident W_hh columns [0, NREG)
        #pragma unroll
        for (int c = 0; c < NREG_C; ++c) {
            uint4 hc = hb4[c];                      // broadcast read
            acc = dot2f(wreg[4 * c + 0], hc.x, acc);
            acc = dot2f(wreg[4 * c + 1], hc.y, acc);
            acc = dot2f(wreg[4 * c + 2], hc.z, acc);
            acc = dot2f(wreg[4 * c + 3], hc.w, acc);
        }

        // LDS-resident W_hh columns [NREG, 512)
        #pragma unroll
        for (int c = 0; c < NLDS_C; ++c) {
            uint4 wc = *(const uint4*)&sm.wlds[(size_t)(c * HID + tid) * 8];
            uint4 hc = hb4[NREG_C + c];
            acc = dot2f(wc.x, hc.x, acc);
            acc = dot2f(wc.y, hc.y, acc);
            acc = dot2f(wc.z, hc.z, acc);
            acc = dot2f(wc.w, hc.w, acc);
        }

        float hnew = tanhf(acc);
        sm.hbuf[1 - p][tid] = (_Float16)hnew;       // write other buffer: race-free

        // commit prefetched x group mid-window (load has had 5 steps to land)
        if (lt == 5 && g + 1 < NGROUPS) {
            const int r = tid >> 6, c = tid & 63;
            sm.xbuf[(g + 1) & 1][r][c] = (_Float16)xnext;
        }

        __syncthreads();                             // one barrier per step
        hval = hnew;
    }

    // ---------------- outputs: (last_step_features, h_n) -- both final h ---
    out[(size_t)b * HID + tid] = hval;
    out[(size_t)BATCH * HID + (size_t)b * HID + tid] = hval;
}

extern "C" void kernel_launch(void* const* d_in, const int* in_sizes, int n_in,
                              void* d_out, int out_size, void* d_ws, size_t ws_size,
                              hipStream_t stream) {
    (void)in_sizes; (void)n_in; (void)out_size; (void)d_ws; (void)ws_size;
    const float* x    = (const float*)d_in[0];
    const float* h0   = (const float*)d_in[1];
    const float* W_ih = (const float*)d_in[2];
    const float* W_hh = (const float*)d_in[3];
    const float* b_ih = (const float*)d_in[4];
    const float* b_hh = (const float*)d_in[5];
    float* out = (float*)d_out;

    hipLaunchKernelGGL(rnn_persist_kernel, dim3(BATCH), dim3(512), 0, stream,
                       x, h0, W_ih, W_hh, b_ih, b_hh, out);
}

// Round 2
// 962.314 us; speedup vs baseline: 1.1897x; 1.1897x over previous
//
#include <hip/hip_runtime.h>
#include <stdint.h>

#define BATCH 256
#define SEQ   512
#define INDIM 64
#define HID   512

typedef _Float16 half2_t __attribute__((ext_vector_type(2)));

__device__ __forceinline__ float dot2f(uint32_t w, uint32_t h, float acc) {
    return __builtin_amdgcn_fdot2(__builtin_bit_cast(half2_t, w),
                                  __builtin_bit_cast(half2_t, h), acc, false);
}
__device__ __forceinline__ uint32_t pack2(float a, float b) {
    half2_t h; h[0] = (_Float16)a; h[1] = (_Float16)b;
    return __builtin_bit_cast(uint32_t, h);
}
// exchange-with-partner-and-add via DPP (quad_perm), all lanes execute
template<int CTRL>
__device__ __forceinline__ float dpp_sum(float x) {
    int xi = __builtin_bit_cast(int, x);
    int yi = __builtin_amdgcn_mov_dpp(xi, CTRL, 0xF, 0xF, true);
    return x + __builtin_bit_cast(float, yi);
}
// xor-4 partner sum via ds_swizzle (BitMode: xor=4, and=0x1F)
__device__ __forceinline__ float swz4_sum(float x) {
    int xi = __builtin_bit_cast(int, x);
    int yi = __builtin_amdgcn_ds_swizzle(xi, 0x101F);
    return x + __builtin_bit_cast(float, yi);
}

struct Smem {
    uint4     wl[16][512];      // W rows 6,7 per thread-group: [v*8+c][t], 128 KB
    _Float16  hbuf[2][8][72];   // h double-buffer, slice-padded (72) -> conflict-free
};

#define DOT4(accv, wrow, hc) \
    accv = dot2f((wrow)[0], hc.x, accv); accv = dot2f((wrow)[1], hc.y, accv); \
    accv = dot2f((wrow)[2], hc.z, accv); accv = dot2f((wrow)[3], hc.w, accv);

__global__ __launch_bounds__(512, 2)
void rnn_ksplit_kernel(const float* __restrict__ x,
                       const float* __restrict__ h0,
                       const float* __restrict__ W_ih,
                       const float* __restrict__ W_hh,
                       const float* __restrict__ b_ih,
                       const float* __restrict__ b_hh,
                       float* __restrict__ out)
{
    __shared__ Smem sm;
    const int t = threadIdx.x;        // final owner of hidden row t
    const int b = blockIdx.x;         // batch element
    const int s = t & 7;              // k-slice: k in [s*64, s*64+64)
    const int rbase = t & ~7;         // 8-row group base

    // ---- W_hh rows rbase..rbase+5 (k-slice s) into registers: 192 packed ----
    uint32_t wreg[6][32];
    #pragma unroll
    for (int j = 0; j < 6; ++j) {
        const float* wr = W_hh + (size_t)(rbase + j) * HID + s * 64;
        #pragma unroll
        for (int q = 0; q < 16; ++q) {
            float4 v4 = ((const float4*)wr)[q];
            wreg[j][2*q]   = pack2(v4.x, v4.y);
            wreg[j][2*q+1] = pack2(v4.z, v4.w);
        }
    }
    // ---- W_hh rows rbase+6, rbase+7 (k-slice s) into LDS (chunk-major) ----
    #pragma unroll
    for (int v = 0; v < 2; ++v) {
        const float* wr = W_hh + (size_t)(rbase + 6 + v) * HID + s * 64;
        #pragma unroll
        for (int c = 0; c < 8; ++c) {
            float4 aa = ((const float4*)wr)[2*c];
            float4 bb = ((const float4*)wr)[2*c+1];
            uint4 wv;
            wv.x = pack2(aa.x, aa.y); wv.y = pack2(aa.z, aa.w);
            wv.z = pack2(bb.x, bb.y); wv.w = pack2(bb.z, bb.w);
            sm.wl[v*8 + c][t] = wv;
        }
    }
    // ---- W_ih rows rbase..rbase+7, i-slice s*8..s*8+8: 32 packed ----
    uint32_t wih[8][4];
    #pragma unroll
    for (int j = 0; j < 8; ++j) {
        const float* wr = W_ih + (size_t)(rbase + j) * INDIM + s * 8;
        float4 aa = ((const float4*)wr)[0];
        float4 bb = ((const float4*)wr)[1];
        wih[j][0] = pack2(aa.x, aa.y); wih[j][1] = pack2(aa.z, aa.w);
        wih[j][2] = pack2(bb.x, bb.y); wih[j][3] = pack2(bb.z, bb.w);
    }

    const float bsum = b_ih[t] + b_hh[t];
    sm.hbuf[0][t >> 6][t & 63] = (_Float16)h0[(size_t)b * HID + t];

    const float* xbase = x + (size_t)b * SEQ * INDIM + s * 8;
    float4 xa = ((const float4*)xbase)[0];          // x_0 slice, prefetched
    float4 xb = ((const float4*)xbase)[1];

    const bool b0 = (s & 1) != 0, b1 = (s & 2) != 0, b2 = (s & 4) != 0;

    __syncthreads();

    float hlast = 0.f;
    #pragma unroll 1
    for (int tt = 0; tt < SEQ; ++tt) {
        // prefetch x slice for step tt+1 (full step of latency cover)
        const int tn = (tt + 1 < SEQ) ? tt + 1 : tt;
        const float* xp = xbase + (size_t)tn * INDIM;
        float4 xa_n = ((const float4*)xp)[0];
        float4 xb_n = ((const float4*)xp)[1];

        const int par = tt & 1;
        float a0=0,a1=0,a2=0,a3=0,a4=0,a5=0,a6=0,a7=0;
        const uint4* hp = (const uint4*)&sm.hbuf[par][s][0];

        #pragma unroll
        for (int c = 0; c < 8; ++c) {
            uint4 hc = hp[c];                 // 8 f16 of h, slice s
            uint4 w6 = sm.wl[c][t];           // row rbase+6 chunk
            uint4 w7 = sm.wl[8 + c][t];       // row rbase+7 chunk
            DOT4(a0, &wreg[0][4*c], hc);
            DOT4(a1, &wreg[1][4*c], hc);
            DOT4(a2, &wreg[2][4*c], hc);
            DOT4(a3, &wreg[3][4*c], hc);
            DOT4(a4, &wreg[4][4*c], hc);
            DOT4(a5, &wreg[5][4*c], hc);
            a6 = dot2f(w6.x, hc.x, a6); a6 = dot2f(w6.y, hc.y, a6);
            a6 = dot2f(w6.z, hc.z, a6); a6 = dot2f(w6.w, hc.w, a6);
            a7 = dot2f(w7.x, hc.x, a7); a7 = dot2f(w7.y, hc.y, a7);
            a7 = dot2f(w7.z, hc.z, a7); a7 = dot2f(w7.w, hc.w, a7);
        }

        // x-projection contribution (i-slice s*8..s*8+8) for all 8 rows
        {
            uint32_t xp0 = pack2(xa.x, xa.y), xp1 = pack2(xa.z, xa.w);
            uint32_t xp2 = pack2(xb.x, xb.y), xp3 = pack2(xb.z, xb.w);
            uint4 xc; xc.x = xp0; xc.y = xp1; xc.z = xp2; xc.w = xp3;
            DOT4(a0, wih[0], xc); DOT4(a1, wih[1], xc);
            DOT4(a2, wih[2], xc); DOT4(a3, wih[3], xc);
            DOT4(a4, wih[4], xc); DOT4(a5, wih[5], xc);
            DOT4(a6, wih[6], xc); DOT4(a7, wih[7], xc);
        }

        // ---- butterfly reduce over the 8 k-slices (lanes t&~7 .. t|7) ----
        // round 1: xor1 via DPP quad_perm(1,0,3,2)=0xB1
        float t0 = dpp_sum<0xB1>(a0), u0 = dpp_sum<0xB1>(a1);
        float t1 = dpp_sum<0xB1>(a2), u1 = dpp_sum<0xB1>(a3);
        float t2 = dpp_sum<0xB1>(a4), u2 = dpp_sum<0xB1>(a5);
        float t3 = dpp_sum<0xB1>(a6), u3 = dpp_sum<0xB1>(a7);
        float q0 = b0 ? u0 : t0;   // tracks row rbase + 0 + (s&1)
        float q1 = b0 ? u1 : t1;   // rbase + 2 + (s&1)
        float q2 = b0 ? u2 : t2;   // rbase + 4 + (s&1)
        float q3 = b0 ? u3 : t3;   // rbase + 6 + (s&1)
        // round 2: xor2 via DPP quad_perm(2,3,0,1)=0x4E
        float r0a = dpp_sum<0x4E>(q0), r0b = dpp_sum<0x4E>(q1);
        float r1a = dpp_sum<0x4E>(q2), r1b = dpp_sum<0x4E>(q3);
        float r0 = b1 ? r0b : r0a; // rbase + (s&3)
        float r1 = b1 ? r1b : r1a; // rbase + 4 + (s&3)
        // round 3: xor4 via ds_swizzle
        float f0 = swz4_sum(r0), f1 = swz4_sum(r1);
        float acc = (b2 ? f1 : f0) + bsum;   // full dot for row t

        // fast tanh: 1 - 2/(e^{2x}+1); saturates correctly at +-inf
        float e  = __expf(2.0f * acc);
        float th = 1.0f - 2.0f * __builtin_amdgcn_rcpf(e + 1.0f);

        sm.hbuf[1 - par][t >> 6][t & 63] = (_Float16)th;
        hlast = th;
        xa = xa_n; xb = xb_n;
        __syncthreads();
    }

    out[(size_t)b * HID + t] = hlast;
    out[(size_t)BATCH * HID + (size_t)b * HID + t] = hlast;
}

extern "C" void kernel_launch(void* const* d_in, const int* in_sizes, int n_in,
                              void* d_out, int out_size, void* d_ws, size_t ws_size,
                              hipStream_t stream) {
    (void)in_sizes; (void)n_in; (void)out_size; (void)d_ws; (void)ws_size;
    const float* x    = (const float*)d_in[0];
    const float* h0   = (const float*)d_in[1];
    const float* W_ih = (const float*)d_in[2];
    const float* W_hh = (const float*)d_in[3];
    const float* b_ih = (const float*)d_in[4];
    const float* b_hh = (const float*)d_in[5];
    float* out = (float*)d_out;

    hipLaunchKernelGGL(rnn_ksplit_kernel, dim3(BATCH), dim3(512), 0, stream,
                       x, h0, W_ih, W_hh, b_ih, b_hh, out);
}